// Round 2
// 1862.405 us; speedup vs baseline: 1.3309x; 1.3309x over previous
//
#include <hip/hip_runtime.h>

// ---------------------------------------------------------------------------
// ScaledDotProductAttention with mask + deterministic JAX-threefry dropout.
// B=8 H=16 S=1024 D=64, fp32. Outputs: [output | attn_weights] concatenated.
// Round 3b: eliminate the LDS-per-FMA bottleneck (compile fix: nontemporal
// float4 stores via ext_vector_type).
//   - Phase 1 (QK^T): K row per lane in VGPRs (global->reg, L2), Q rows are
//     wave-uniform loads (scalarized). Zero LDS in the inner loop.
//   - Phase 2: softmax + mask + threefry dropout fully in registers; wave
//     shfl_xor reductions + tiny cross-wave LDS scratch.
//   - Phase 3 (PV): weights transposed in LDS (WT[k][q], 48B rows,
//     conflict-free b128 reads, 2 reads per 32 FMAs); V from global (L2).
// ---------------------------------------------------------------------------

constexpr int Bc = 8, Hc = 16, Sc = 1024, Dc = 64;
constexpr int TQ  = 8;     // q-rows per block
constexpr int WTP = 12;    // WT row stride in floats (48B, 16B-aligned, odd*16B)

typedef float v4f __attribute__((ext_vector_type(4)));

#define TF_ROUND(x0, x1, r) { x0 += x1; x1 = ((x1 << (r)) | (x1 >> (32 - (r)))); x1 ^= x0; }

// Exact JAX threefry2x32 (20 rounds, 5 key injections).
__host__ __device__ __forceinline__ void threefry2x32(unsigned k0, unsigned k1,
                                                      unsigned x0, unsigned x1,
                                                      unsigned& o0, unsigned& o1) {
  const unsigned k2 = k0 ^ k1 ^ 0x1BD11BDAu;
  x0 += k0; x1 += k1;
  TF_ROUND(x0, x1, 13) TF_ROUND(x0, x1, 15) TF_ROUND(x0, x1, 26) TF_ROUND(x0, x1, 6)
  x0 += k1; x1 += k2 + 1u;
  TF_ROUND(x0, x1, 17) TF_ROUND(x0, x1, 29) TF_ROUND(x0, x1, 16) TF_ROUND(x0, x1, 24)
  x0 += k2; x1 += k0 + 2u;
  TF_ROUND(x0, x1, 13) TF_ROUND(x0, x1, 15) TF_ROUND(x0, x1, 26) TF_ROUND(x0, x1, 6)
  x0 += k0; x1 += k1 + 3u;
  TF_ROUND(x0, x1, 17) TF_ROUND(x0, x1, 29) TF_ROUND(x0, x1, 16) TF_ROUND(x0, x1, 24)
  x0 += k1; x1 += k2 + 4u;
  TF_ROUND(x0, x1, 13) TF_ROUND(x0, x1, 15) TF_ROUND(x0, x1, 26) TF_ROUND(x0, x1, 6)
  x0 += k2; x1 += k0 + 5u;
  o0 = x0; o1 = x1;
}

__global__ __launch_bounds__(256, 3)
void attn_fused(const float* __restrict__ Qg, const float* __restrict__ Kg,
                const float* __restrict__ Vg, const int* __restrict__ Mg,
                float* __restrict__ Og, float* __restrict__ Ag,
                unsigned key0, unsigned key1)
{
  // WT[k][q]: transposed score/weight buffer. 48B rows -> b128 reads by
  // consecutive-k lanes are 2-way (free) bank aliased.
  __shared__ __align__(16) float WT[Sc][WTP];   // 48 KB
  __shared__ float REDm[4][8];                  // cross-wave max scratch
  __shared__ float REDs[4][8];                  // cross-wave sum scratch

  const int tid = threadIdx.x;
  const int w   = tid >> 6;          // wave 0..3
  const int l   = tid & 63;          // lane
  const int h   = blockIdx.y;
  const int b   = blockIdx.z;
  const int q0  = blockIdx.x * TQ;
  const size_t bh = (size_t)b * Hc + h;

  const float* __restrict__ Kb = Kg + bh * Sc * Dc;
  const float* __restrict__ Vb = Vg + bh * Sc * Dc;
  const float* __restrict__ Qb = Qg + bh * Sc * Dc + (size_t)q0 * Dc;

  // ---------------- phase 1: scores = (Q.K)/8 ----------------
  // Lane owns K row k = kb*256 + w*64 + l in registers; loops 8 q with
  // wave-uniform Q loads. Scores parked in this thread's own WT rows.
  #pragma unroll 1
  for (int kb = 0; kb < 4; ++kb) {
    const int k = kb * 256 + w * 64 + l;
    const float4* __restrict__ Krow = (const float4*)(Kb + (size_t)k * Dc);
    float4 kr[16];
    #pragma unroll
    for (int j = 0; j < 16; ++j) kr[j] = Krow[j];
    float acc[8];
    #pragma unroll
    for (int q = 0; q < 8; ++q) {
      const float4* __restrict__ Qrow = (const float4*)(Qb + q * Dc);  // uniform
      float a = 0.f;
      #pragma unroll
      for (int j = 0; j < 16; ++j) {
        const float4 qv = Qrow[j];
        a = fmaf(kr[j].x, qv.x, a);
        a = fmaf(kr[j].y, qv.y, a);
        a = fmaf(kr[j].z, qv.z, a);
        a = fmaf(kr[j].w, qv.w, a);
      }
      acc[q] = a * 0.125f;           // /sqrt(64), exact pow2 (matches ref order)
    }
    // park in own rows (same-thread readback; no sync needed)
    *(float4*)&WT[k][0] = make_float4(acc[0], acc[1], acc[2], acc[3]);
    *(float4*)&WT[k][4] = make_float4(acc[4], acc[5], acc[6], acc[7]);
  }

  // ---------------- phase 2: mask, softmax, dropout ----------------
  const float NEG = -__builtin_inff();
  float sv[4][8];                    // [kb][q], fully static-indexed
  #pragma unroll
  for (int kb = 0; kb < 4; ++kb) {
    const int k = kb * 256 + w * 64 + l;
    const float4 lo = *(const float4*)&WT[k][0];
    const float4 hi = *(const float4*)&WT[k][4];
    sv[kb][0] = lo.x; sv[kb][1] = lo.y; sv[kb][2] = lo.z; sv[kb][3] = lo.w;
    sv[kb][4] = hi.x; sv[kb][5] = hi.y; sv[kb][6] = hi.z; sv[kb][7] = hi.w;
    const int* __restrict__ mcol = Mg + (size_t)b * Sc * Sc + k;  // + (q0+q)*Sc
    #pragma unroll
    for (int q = 0; q < 8; ++q)
      if (mcol[(size_t)(q0 + q) * Sc] == 0) sv[kb][q] = NEG;
  }

  // row max: in-thread over kb, wave shfl, cross-wave via LDS
  float mx[8];
  #pragma unroll
  for (int q = 0; q < 8; ++q) {
    float m = fmaxf(fmaxf(sv[0][q], sv[1][q]), fmaxf(sv[2][q], sv[3][q]));
    #pragma unroll
    for (int off = 32; off > 0; off >>= 1) m = fmaxf(m, __shfl_xor(m, off));
    if (l == 0) REDm[w][q] = m;
  }
  __syncthreads();
  #pragma unroll
  for (int q = 0; q < 8; ++q)
    mx[q] = fmaxf(fmaxf(REDm[0][q], REDm[1][q]), fmaxf(REDm[2][q], REDm[3][q]));

  // exp + row sum
  #pragma unroll
  for (int kb = 0; kb < 4; ++kb)
    #pragma unroll
    for (int q = 0; q < 8; ++q)
      sv[kb][q] = __expf(sv[kb][q] - mx[q]);   // masked -> exp(-inf)=0
  #pragma unroll
  for (int q = 0; q < 8; ++q) {
    float s = (sv[0][q] + sv[1][q]) + (sv[2][q] + sv[3][q]);
    #pragma unroll
    for (int off = 32; off > 0; off >>= 1) s += __shfl_xor(s, off);
    if (l == 0) REDs[w][q] = s;
  }
  __syncthreads();
  float inv9[8];
  #pragma unroll
  for (int q = 0; q < 8; ++q)
    inv9[q] = 1.0f / (((REDs[0][q] + REDs[1][q]) + (REDs[2][q] + REDs[3][q])) * 0.9f);

  // dropout bits: bits[i] = o0^o1 of threefry2x32(key, (0, i)); keep if u<0.9
  unsigned keep = 0u;
  const unsigned ibase = ((unsigned)(((unsigned)b * Hc + h) * Sc + q0)) * (unsigned)Sc
                         + (unsigned)(w * 64 + l);
  #pragma unroll 8
  for (int t2 = 0; t2 < 32; ++t2) {            // bit t2 = kb*8 + q
    const int kb = t2 >> 3, q = t2 & 7;
    unsigned o0, o1;
    threefry2x32(key0, key1, 0u, ibase + (unsigned)(q * Sc + kb * 256), o0, o1);
    const unsigned bits = o0 ^ o1;
    const float u = __uint_as_float((bits >> 9) | 0x3f800000u) - 1.0f;  // [0,1)
    keep |= (u < 0.9f) ? (1u << t2) : 0u;
  }

  // apply, write attn_weights (streaming) and final weights into WT
  float* __restrict__ Arow = Ag + bh * (size_t)Sc * Sc + (size_t)q0 * Sc;
  #pragma unroll
  for (int kb = 0; kb < 4; ++kb) {
    const int k = kb * 256 + w * 64 + l;
    float wv[8];
    #pragma unroll
    for (int q = 0; q < 8; ++q) {
      wv[q] = ((keep >> (kb * 8 + q)) & 1u) ? sv[kb][q] * inv9[q] : 0.f;
      __builtin_nontemporal_store(wv[q], &Arow[(size_t)q * Sc + k]);
    }
    *(float4*)&WT[k][0] = make_float4(wv[0], wv[1], wv[2], wv[3]);
    *(float4*)&WT[k][4] = make_float4(wv[4], wv[5], wv[6], wv[7]);
  }
  __syncthreads();                   // WT complete for cross-thread reads

  // ---------------- phase 3: output = W . V ----------------
  // thread: ks = tid&15 (k-slice, k = i*16+ks), dq = tid>>4 (d-quad).
  // Per k: 2 b128 WT reads feed 32 FMAs; V float4 direct from global (L2).
  const int ks = tid & 15;
  const int dq = tid >> 4;           // 0..15
  float4 acc[8];
  #pragma unroll
  for (int q = 0; q < 8; ++q) acc[q] = make_float4(0.f, 0.f, 0.f, 0.f);

  #pragma unroll 2
  for (int i = 0; i < 64; ++i) {
    const int k = i * 16 + ks;
    const float4 vv = *(const float4*)(Vb + (size_t)k * Dc + dq * 4);
    const float4 lo = *(const float4*)&WT[k][0];
    const float4 hi = *(const float4*)&WT[k][4];
#define ACCQ(qi, wq) { acc[qi].x = fmaf(wq, vv.x, acc[qi].x); \
                       acc[qi].y = fmaf(wq, vv.y, acc[qi].y); \
                       acc[qi].z = fmaf(wq, vv.z, acc[qi].z); \
                       acc[qi].w = fmaf(wq, vv.w, acc[qi].w); }
    ACCQ(0, lo.x) ACCQ(1, lo.y) ACCQ(2, lo.z) ACCQ(3, lo.w)
    ACCQ(4, hi.x) ACCQ(5, hi.y) ACCQ(6, hi.z) ACCQ(7, hi.w)
#undef ACCQ
  }

  // reduce over the 16 k-slices (lane bits 0..3); dq groups unaffected
  #pragma unroll
  for (int off = 1; off <= 8; off <<= 1) {
    #pragma unroll
    for (int q = 0; q < 8; ++q) {
      acc[q].x += __shfl_xor(acc[q].x, off);
      acc[q].y += __shfl_xor(acc[q].y, off);
      acc[q].z += __shfl_xor(acc[q].z, off);
      acc[q].w += __shfl_xor(acc[q].w, off);
    }
  }
  if ((l & 15) == 0) {
    float* __restrict__ Obase = Og + bh * (size_t)Sc * Dc + (size_t)q0 * Dc + dq * 4;
    #pragma unroll
    for (int q = 0; q < 8; ++q) {
      const v4f t = { acc[q].x, acc[q].y, acc[q].z, acc[q].w };
      __builtin_nontemporal_store(t, (v4f*)(Obase + (size_t)q * Dc));
    }
  }
}

extern "C" void kernel_launch(void* const* d_in, const int* in_sizes, int n_in,
                              void* d_out, int out_size, void* d_ws, size_t ws_size,
                              hipStream_t stream) {
  const float* Qg = (const float*)d_in[0];
  const float* Kg = (const float*)d_in[1];
  const float* Vg = (const float*)d_in[2];
  const int*   Mg = (const int*)d_in[3];
  float* Og = (float*)d_out;
  float* Ag = Og + (size_t)Bc * Hc * Sc * Dc;   // attn_weights after output

  // drop_key = fold_in(key(42), 7) = threefry2x32(key=[0,42], counts=[0,7])
  unsigned k0, k1;
  threefry2x32(0u, 42u, 0u, 7u, k0, k1);

  dim3 grid(Sc / TQ, Hc, Bc);   // (128, 16, 8)
  attn_fused<<<grid, 256, 0, stream>>>(Qg, Kg, Vg, Mg, Og, Ag, k0, k1);
}